// Round 6
// baseline (1236.293 us; speedup 1.0000x reference)
//
#include <hip/hip_runtime.h>

// GraphSAGE 3-layer forward, MI355X. Round 15:
//   R14 = 268us. Fused layers (43+50) understood & fabric-bound; remaining
//   ~175us is memset + setup_scatter + place/masks + gather64 + 5 launch
//   boundaries. Change: ONE persistent kernel (1792 blocks = 7/CU, lb(256,8)
//   guarantees >=8/CU co-residency) running all 5 phases with hand-rolled
//   agent-scope grid barriers (release on arrive -> wbl2; acquire fence on
//   exit -> inv; same cache ops as kernel boundaries). Phase code identical
//   to R14, grid-strided. F stored f16 (-13MB). 6 GPU ops -> memset + 1.

constexpr int N = 50000;
constexpr int E = 800000;
constexpr int NBUCK = (N + 255) / 256;    // 196
constexpr int CE = 2048;
constexpr int NEB = (E + CE - 1) / CE;    // 391
constexpr int SLOT = 5632;
constexpr int NBLK = 1792;                // 7 blocks/CU (capacity 8: margin)
constexpr int CONVB = N * 128 / 8 / 256;  // 3125
constexpr int MASKB = (N * 128) / (8 * 256);  // 3125
static_assert(N % 16 == 0, "16-row tiles");
static_assert(N <= 65536, "u16 packing");

typedef _Float16 f16x8 __attribute__((ext_vector_type(8)));
typedef _Float16 f16x4 __attribute__((ext_vector_type(4)));
typedef _Float16 f16x2 __attribute__((ext_vector_type(2)));
typedef float f32x4 __attribute__((ext_vector_type(4)));

__device__ int g_cnt = 0, g_gen = 0;      // .bss zero at load; invariant after

// grid barrier: all NBLK blocks. Release on arrive (L2 writeback), acquire
// fence on exit (L2 invalidate) -- replicates kernel-boundary coherence.
__device__ __forceinline__ void gridbar() {
  __syncthreads();
  if (threadIdx.x == 0) {
    int g = __hip_atomic_load(&g_gen, __ATOMIC_RELAXED, __HIP_MEMORY_SCOPE_AGENT);
    int v = __hip_atomic_fetch_add(&g_cnt, 1, __ATOMIC_RELEASE, __HIP_MEMORY_SCOPE_AGENT);
    if (v == NBLK - 1) {
      __hip_atomic_store(&g_cnt, 0, __ATOMIC_RELAXED, __HIP_MEMORY_SCOPE_AGENT);
      __hip_atomic_store(&g_gen, g + 1, __ATOMIC_RELEASE, __HIP_MEMORY_SCOPE_AGENT);
    } else {
      while (__hip_atomic_load(&g_gen, __ATOMIC_RELAXED, __HIP_MEMORY_SCOPE_AGENT) == g)
        __builtin_amdgcn_s_sleep(2);
    }
    __builtin_amdgcn_fence(__ATOMIC_ACQUIRE, "agent");
  }
  __syncthreads();
}

// Wf[((ct*KB+kb)*64+lane)*8+j] = Wcat[ct*16+(lane&15)][kb*32+(lane>>4)*8+j]
__device__ __forceinline__ void wfrag_build(int idx, int KB, const float* wl,
                                            const float* wr, _Float16* wf) {
  int j = idx & 7;
  int lane = (idx >> 3) & 63;
  int kb = (idx >> 9) % KB;
  int ct = (idx >> 9) / KB;
  int c = ct * 16 + (lane & 15);
  int k = kb * 32 + (lane >> 4) * 8 + j;
  float v = (k < 128) ? wl[c * 128 + k] : wr[c * 128 + (k - 128)];
  wf[idx] = (_Float16)v;
}

// gather-mean of H[src,:] cols [4*ll, 4*ll+4) over node's segment -> f16x4
__device__ __forceinline__ f16x4 gather_mean128(
    const _Float16* __restrict__ H, const int* __restrict__ elist,
    int e0, int d, int ll) {
  float a0 = 0.f, a1 = 0.f, a2 = 0.f, a3 = 0.f;
  const int e1 = e0 + d;
  int e = e0;
  for (; e + 16 <= e1; e += 16) {
    int4 q0 = *(const int4*)(elist + e);
    int4 q1 = *(const int4*)(elist + e + 4);
    int4 q2 = *(const int4*)(elist + e + 8);
    int4 q3 = *(const int4*)(elist + e + 12);
    int s[16] = {q0.x, q0.y, q0.z, q0.w, q1.x, q1.y, q1.z, q1.w,
                 q2.x, q2.y, q2.z, q2.w, q3.x, q3.y, q3.z, q3.w};
    f16x4 v[16];
#pragma unroll
    for (int u = 0; u < 16; ++u)
      v[u] = *(const f16x4*)(H + (size_t)s[u] * 128 + ll * 4);
#pragma unroll
    for (int u = 0; u < 16; ++u) {
      a0 += (float)v[u][0]; a1 += (float)v[u][1];
      a2 += (float)v[u][2]; a3 += (float)v[u][3];
    }
  }
  for (; e + 4 <= e1; e += 4) {
    int4 q4 = *(const int4*)(elist + e);
    int s[4] = {q4.x, q4.y, q4.z, q4.w};
    f16x4 v[4];
#pragma unroll
    for (int u = 0; u < 4; ++u)
      v[u] = *(const f16x4*)(H + (size_t)s[u] * 128 + ll * 4);
#pragma unroll
    for (int u = 0; u < 4; ++u) {
      a0 += (float)v[u][0]; a1 += (float)v[u][1];
      a2 += (float)v[u][2]; a3 += (float)v[u][3];
    }
  }
  for (; e < e1; ++e) {
    f16x4 v = *(const f16x4*)(H + (size_t)elist[e] * 128 + ll * 4);
    a0 += (float)v[0]; a1 += (float)v[1];
    a2 += (float)v[2]; a3 += (float)v[3];
  }
  float inv = 1.0f / (float)max(d, 1);
  f16x4 o;
  o[0] = (_Float16)(a0 * inv); o[1] = (_Float16)(a1 * inv);
  o[2] = (_Float16)(a2 * inv); o[3] = (_Float16)(a3 * inv);
  return o;
}

__global__ __launch_bounds__(256, 8) void mega_kernel(
    const int* __restrict__ src, const int* __restrict__ dst,
    int* __restrict__ bcur, unsigned* __restrict__ T,
    const float* __restrict__ x,
    const float* __restrict__ u1, const float* __restrict__ u2,
    const float* __restrict__ wl0, const float* __restrict__ wr0,
    const float* __restrict__ wl1, const float* __restrict__ wr1,
    const float* __restrict__ wl2, const float* __restrict__ wr2,
    const float* __restrict__ bl0, const float* __restrict__ bl1,
    const float* __restrict__ bl2,
    _Float16* __restrict__ HA, _Float16* __restrict__ HB,
    _Float16* __restrict__ Y2, _Float16* __restrict__ Fh,
    int* __restrict__ offs, int* __restrict__ deg, int* __restrict__ elist,
    unsigned* __restrict__ mk1, unsigned* __restrict__ mk2,
    _Float16* __restrict__ wf0, _Float16* __restrict__ wf1,
    _Float16* __restrict__ wfZ, float* __restrict__ out) {
  __shared__ __align__(16) unsigned char smem[13312];
  const int t = threadIdx.x;
  const int bid = blockIdx.x;

  // ---------------- phase 0: scatter | convert | wfrag tables -------------
  {
    unsigned* sorted = (unsigned*)smem;               // [2048]
    int* hist = (int*)(smem + 8192);                  // [256] x5
    int* scan = hist + 256;
    int* excl = scan + 256;
    int* lcur = excl + 256;
    int* gbase = lcur + 256;
    for (int vb = bid; vb < NEB + CONVB + 320; vb += NBLK) {
      __syncthreads();                                // LDS reuse across iters
      if (vb < NEB) {                                 // scatter chunk
        const int e0 = vb * CE;
        const int nval = min(CE, E - e0);
        hist[t] = 0;
        __syncthreads();
        for (int i = t; i < nval; i += 256) atomicAdd(&hist[dst[e0 + i] >> 8], 1);
        __syncthreads();
        const int h = hist[t];
        scan[t] = h;
        __syncthreads();
        for (int off = 1; off < 256; off <<= 1) {
          int u = (t >= off) ? scan[t - off] : 0;
          __syncthreads();
          scan[t] += u;
          __syncthreads();
        }
        excl[t] = scan[t] - h;
        lcur[t] = scan[t] - h;
        gbase[t] = (t < NBUCK && h > 0) ? (t * SLOT + atomicAdd(&bcur[t], h)) : 0;
        __syncthreads();
        for (int i = t; i < nval; i += 256) {
          int e = e0 + i;
          int d = dst[e];
          int p = atomicAdd(&lcur[d >> 8], 1);
          sorted[p] = ((unsigned)d << 16) | (unsigned)src[e];
        }
        __syncthreads();
        for (int i = t; i < nval; i += 256) {
          unsigned pk = sorted[i];
          int bb = pk >> 24;
          T[gbase[bb] + (i - excl[bb])] = pk;
        }
      } else {
        const int b2 = vb - NEB;
        if (b2 < CONVB) {                             // x f32 -> HA f16
          int i = b2 * 256 + t;
          float4 a = ((const float4*)x)[i * 2];
          float4 c = ((const float4*)x)[i * 2 + 1];
          f16x8 v;
          v[0] = (_Float16)a.x; v[1] = (_Float16)a.y; v[2] = (_Float16)a.z; v[3] = (_Float16)a.w;
          v[4] = (_Float16)c.x; v[5] = (_Float16)c.y; v[6] = (_Float16)c.z; v[7] = (_Float16)c.w;
          ((f16x8*)HA)[i] = v;
        } else if (b2 < CONVB + 128) {
          wfrag_build((b2 - CONVB) * 256 + t, 8, wl0, wr0, wf0);
        } else if (b2 < CONVB + 256) {
          wfrag_build((b2 - CONVB - 128) * 256 + t, 8, wl1, wr1, wf1);
        } else {                                      // wfZ (64 vblocks)
          int idx = (b2 - CONVB - 256) * 256 + t;
          int j = idx & 7;
          int lane = (idx >> 3) & 63;
          int kb = (idx >> 9) & 3;
          int ct = idx >> 11;
          int c = ct * 16 + (lane & 15);
          int k = kb * 32 + (lane >> 4) * 8 + j;
          float v = (c < 64) ? wl2[c * 128 + k] : wr2[(c - 64) * 128 + k];
          wfZ[idx] = (_Float16)v;
        }
      }
    }
  }
  gridbar();

  // ---------------- phase 1: place + dropout masks -------------------------
  {
    int* dcnt = (int*)smem;                           // [256] x3
    int* s = dcnt + 256;
    int* ncur = s + 256;
    for (int vb = bid; vb < NBUCK + 2 * MASKB; vb += NBLK) {
      __syncthreads();
      if (vb >= NBUCK) {                              // bit-pack masks
        int mb = vb - NBUCK;
        const float* Us = (mb < MASKB) ? u1 : u2;
        unsigned* MKs = (mb < MASKB) ? mk1 : mk2;
        int bb = (mb < MASKB) ? mb : (mb - MASKB);
#pragma unroll
        for (int k = 0; k < 8; ++k) {
          int i = (bb * 8 + k) * 256 + t;
          unsigned long long m = __ballot(Us[i] >= 0.3f);
          int lt = t & 63;
          if (lt == 0) MKs[i >> 5] = (unsigned)m;
          else if (lt == 32) MKs[i >> 5] = (unsigned)(m >> 32);
        }
      } else {                                        // bucket place
        const int lo = vb * SLOT;
        const int hi = lo + bcur[vb];
        dcnt[t] = 0;
        __syncthreads();
        for (int i = lo + t; i < hi; i += 256) atomicAdd(&dcnt[(T[i] >> 16) & 255], 1);
        __syncthreads();
        const int v = dcnt[t];
        const int pv = (v + 3) & ~3;
        s[t] = pv;
        __syncthreads();
        for (int off = 1; off < 256; off <<= 1) {
          int u = (t >= off) ? s[t - off] : 0;
          __syncthreads();
          s[t] += u;
          __syncthreads();
        }
        const int base = lo + s[t] - pv;
        const int node = vb * 256 + t;
        if (node < N) { offs[node] = base; deg[node] = v; }
        ncur[t] = base;
        __syncthreads();
        for (int i = lo + t; i < hi; i += 256) {
          unsigned pk = T[i];
          int pos = atomicAdd(&ncur[(pk >> 16) & 255], 1);
          elist[pos] = (int)(pk & 0xffffu);
        }
      }
    }
  }
  gridbar();

  // ---------------- phase 2: layer 0 (gather-mean + GEMM) ------------------
  {
    _Float16 (*Af)[64][8] = (_Float16(*)[64][8])smem;    // [8][64][8] 8KB
    const int lane = t & 63;
    const int w = t >> 6;
    const int n16 = lane & 15;
    const int qq = lane >> 4;
    const int colbase = w * 32;
    const int hw = t >> 5;
    const int ll = t & 31;
    const int kbb = ll >> 3, qg = (ll >> 1) & 3, jg = (ll & 1) * 4;
    for (int vb = bid; vb < N / 16; vb += NBLK) {
      __syncthreads();                                // Af reuse across iters
      const int rowbase = vb * 16;
      {   // 1a: own rows
        int r = t >> 4, o = t & 15;
        f16x8 v = *(const f16x8*)(HA + (size_t)(rowbase + r) * 128 + o * 8);
        *(f16x8*)&Af[4 + (o >> 2)][(o & 3) * 16 + r][0] = v;
      }
#pragma unroll 1
      for (int i = 0; i < 2; ++i) {                   // 1b: gather-mean
        int r = hw * 2 + i;
        int node = rowbase + r;
        f16x4 o = gather_mean128(HA, elist, offs[node], deg[node], ll);
        *(f16x4*)&Af[kbb][qg * 16 + r][jg] = o;
      }
      __syncthreads();
      f32x4 acc[2];
      acc[0] = (f32x4){0.f, 0.f, 0.f, 0.f};
      acc[1] = (f32x4){0.f, 0.f, 0.f, 0.f};
#pragma unroll
      for (int kb = 0; kb < 8; ++kb) {
        f16x8 a = *(const f16x8*)&Af[kb][lane][0];
#pragma unroll
        for (int ct = 0; ct < 2; ++ct) {
          const int ctg = w * 2 + ct;
          f16x8 b = *(const f16x8*)(wf0 + ((size_t)(ctg * 8 + kb) * 64 + lane) * 8);
          acc[ct] = __builtin_amdgcn_mfma_f32_16x16x32_f16(a, b, acc[ct], 0, 0, 0);
        }
      }
#pragma unroll
      for (int r = 0; r < 4; ++r) {
        int row = rowbase + qq * 4 + r;
        unsigned mw = mk1[(size_t)row * 4 + w];
#pragma unroll
        for (int ct = 0; ct < 2; ++ct) {
          const int col = colbase + ct * 16 + n16;
          float v = fmaxf(acc[ct][r] + bl0[col], 0.f);
          v = ((mw >> (ct * 16 + n16)) & 1u) ? v * (1.0f / 0.7f) : 0.0f;
          HB[(size_t)row * 128 + col] = (_Float16)v;
        }
      }
    }
  }
  gridbar();

  // ---------------- phase 3: layer 1 + layer-2 GEMM ------------------------
  {
    _Float16 (*Af)[64][8] = (_Float16(*)[64][8])smem;    // 8KB
    _Float16 (*Zf)[136] = (_Float16(*)[136])(smem + 8192);  // [16][136] 4.25KB
    const int lane = t & 63;
    const int w = t >> 6;
    const int n16 = lane & 15;
    const int qq = lane >> 4;
    const int colbase = w * 32;
    const int hw = t >> 5;
    const int ll = t & 31;
    const int kbb = ll >> 3, qg = (ll >> 1) & 3, jg = (ll & 1) * 4;
    for (int vb = bid; vb < N / 16; vb += NBLK) {
      __syncthreads();
      const int rowbase = vb * 16;
      {
        int r = t >> 4, o = t & 15;
        f16x8 v = *(const f16x8*)(HB + (size_t)(rowbase + r) * 128 + o * 8);
        *(f16x8*)&Af[4 + (o >> 2)][(o & 3) * 16 + r][0] = v;
      }
#pragma unroll 1
      for (int i = 0; i < 2; ++i) {
        int r = hw * 2 + i;
        int node = rowbase + r;
        f16x4 o = gather_mean128(HB, elist, offs[node], deg[node], ll);
        *(f16x4*)&Af[kbb][qg * 16 + r][jg] = o;
      }
      __syncthreads();
      f32x4 acc[2];
      acc[0] = (f32x4){0.f, 0.f, 0.f, 0.f};
      acc[1] = (f32x4){0.f, 0.f, 0.f, 0.f};
#pragma unroll
      for (int kb = 0; kb < 8; ++kb) {
        f16x8 a = *(const f16x8*)&Af[kb][lane][0];
#pragma unroll
        for (int ct = 0; ct < 2; ++ct) {
          const int ctg = w * 2 + ct;
          f16x8 b = *(const f16x8*)(wf1 + ((size_t)(ctg * 8 + kb) * 64 + lane) * 8);
          acc[ct] = __builtin_amdgcn_mfma_f32_16x16x32_f16(a, b, acc[ct], 0, 0, 0);
        }
      }
      // h1 -> Zf (relu, dropout), then layer-2 GEMM vs wfZ
#pragma unroll
      for (int r = 0; r < 4; ++r) {
        int row = qq * 4 + r;
        unsigned mw = mk2[(size_t)(rowbase + row) * 4 + w];
#pragma unroll
        for (int ct = 0; ct < 2; ++ct) {
          const int col = colbase + ct * 16 + n16;
          float v = fmaxf(acc[ct][r] + bl1[col], 0.f);
          v = ((mw >> (ct * 16 + n16)) & 1u) ? v * (1.0f / 0.7f) : 0.0f;
          Zf[row][col] = (_Float16)v;
        }
      }
      __syncthreads();
      f32x4 az[2];
      az[0] = (f32x4){0.f, 0.f, 0.f, 0.f};
      az[1] = (f32x4){0.f, 0.f, 0.f, 0.f};
#pragma unroll
      for (int kb = 0; kb < 4; ++kb) {
        f16x8 a = *(const f16x8*)&Zf[n16][kb * 32 + qq * 8];
#pragma unroll
        for (int ct = 0; ct < 2; ++ct) {
          const int ctg = w * 2 + ct;
          f16x8 b = *(const f16x8*)(wfZ + ((size_t)(ctg * 4 + kb) * 64 + lane) * 8);
          az[ct] = __builtin_amdgcn_mfma_f32_16x16x32_f16(a, b, az[ct], 0, 0, 0);
        }
      }
#pragma unroll
      for (int ct = 0; ct < 2; ++ct) {
        const int col = colbase + ct * 16 + n16;
#pragma unroll
        for (int r = 0; r < 4; ++r) {
          int row = rowbase + qq * 4 + r;
          float v = az[ct][r];
          if (col < 64) Y2[(size_t)row * 64 + col] = (_Float16)v;
          else Fh[(size_t)row * 64 + (col - 64)] = (_Float16)(v + bl2[col - 64]);
        }
      }
    }
  }
  gridbar();

  // ---------------- phase 4: gather64 + final add --------------------------
  {
    const int l = t & 31;
    for (int vb = bid; vb < (N + 7) / 8; vb += NBLK) {
      int node = vb * 8 + (t >> 5);
      if (node >= N) continue;
      const int e0 = offs[node];
      const int d = deg[node];
      const int e1 = e0 + d;
      float a0 = 0.f, a1 = 0.f;
      int e = e0;
      for (; e + 16 <= e1; e += 16) {
        int4 q0 = *(const int4*)(elist + e);
        int4 q1 = *(const int4*)(elist + e + 4);
        int4 q2 = *(const int4*)(elist + e + 8);
        int4 q3 = *(const int4*)(elist + e + 12);
        int s[16] = {q0.x, q0.y, q0.z, q0.w, q1.x, q1.y, q1.z, q1.w,
                     q2.x, q2.y, q2.z, q2.w, q3.x, q3.y, q3.z, q3.w};
        f16x2 v[16];
#pragma unroll
        for (int u = 0; u < 16; ++u)
          v[u] = *(const f16x2*)(Y2 + (size_t)s[u] * 64 + l * 2);
#pragma unroll
        for (int u = 0; u < 16; ++u) { a0 += (float)v[u][0]; a1 += (float)v[u][1]; }
      }
      for (; e + 4 <= e1; e += 4) {
        int4 q = *(const int4*)(elist + e);
        int s[4] = {q.x, q.y, q.z, q.w};
        f16x2 v[4];
#pragma unroll
        for (int u = 0; u < 4; ++u)
          v[u] = *(const f16x2*)(Y2 + (size_t)s[u] * 64 + l * 2);
#pragma unroll
        for (int u = 0; u < 4; ++u) { a0 += (float)v[u][0]; a1 += (float)v[u][1]; }
      }
      for (; e < e1; ++e) {
        f16x2 v = *(const f16x2*)(Y2 + (size_t)elist[e] * 64 + l * 2);
        a0 += (float)v[0]; a1 += (float)v[1];
      }
      float inv = 1.0f / (float)max(d, 1);
      f16x2 fv = ((const f16x2*)(Fh + (size_t)node * 64))[l];
      float2 o;
      o.x = (float)fv[0] + a0 * inv;
      o.y = (float)fv[1] + a1 * inv;
      ((float2*)(out + (size_t)node * 64))[l] = o;
    }
  }
}

extern "C" void kernel_launch(void* const* d_in, const int* in_sizes, int n_in,
                              void* d_out, int out_size, void* d_ws, size_t ws_size,
                              hipStream_t stream) {
  const float* x   = (const float*)d_in[0];
  const float* u1  = (const float*)d_in[1];
  const float* u2  = (const float*)d_in[2];
  const float* wl0 = (const float*)d_in[3];
  const float* bl0 = (const float*)d_in[4];
  const float* wr0 = (const float*)d_in[5];
  const float* wl1 = (const float*)d_in[6];
  const float* bl1 = (const float*)d_in[7];
  const float* wr1 = (const float*)d_in[8];
  const float* wl2 = (const float*)d_in[9];
  const float* bl2 = (const float*)d_in[10];
  const float* wr2 = (const float*)d_in[11];
  const int* edge  = (const int*)d_in[12];
  const int* src = edge;
  const int* dst = edge + E;

  // workspace layout
  _Float16* HA  = (_Float16*)d_ws;                 // N x 128 f16
  _Float16* HB  = HA + (size_t)N * 128;            // N x 128 f16
  _Float16* Y2  = HB + (size_t)N * 128;            // N x 64 f16
  _Float16* Fh  = Y2 + (size_t)N * 64;             // N x 64 f16
  int* offs     = (int*)(Fh + (size_t)N * 64);     // N
  int* deg      = offs + N;                        // N
  int* elist    = deg + N;                         // NBUCK*SLOT
  unsigned* T   = (unsigned*)(elist + NBUCK * SLOT);
  int* bcur     = (int*)(T + NBUCK * SLOT);        // NBUCK (counts)
  uintptr_t p = (uintptr_t)(bcur + NBUCK);
  p = (p + 15) & ~(uintptr_t)15;
  _Float16* wf0 = (_Float16*)p;                    // 8*8*512
  _Float16* wf1 = wf0 + 8 * 8 * 512;
  _Float16* wfZ = wf1 + 8 * 8 * 512;               // 8*4*512
  unsigned* mk1 = (unsigned*)(wfZ + 8 * 4 * 512);  // N*4 u32
  unsigned* mk2 = mk1 + (size_t)N * 4;             // N*4 u32

  hipMemsetAsync(bcur, 0, NBUCK * sizeof(int), stream);
  mega_kernel<<<NBLK, 256, 0, stream>>>(
      src, dst, bcur, T, x, u1, u2, wl0, wr0, wl1, wr1, wl2, wr2,
      bl0, bl1, bl2, HA, HB, Y2, Fh, offs, deg, elist, mk1, mk2,
      wf0, wf1, wfZ, (float*)d_out);
}

// Round 7
// 273.531 us; speedup vs baseline: 4.5198x; 4.5198x over previous
//
#include <hip/hip_runtime.h>

// GraphSAGE 3-layer forward, MI355X. Round 16 (= R14 revert + byte cuts):
//   R15 persistent mega-kernel FAILED 4.6x (268->1236us): 1792 spinner waves
//   polling one device-scope cacheline across 8 XCDs floods the coherence
//   fabric; phase imbalance at 4 grid barriers. Lesson: launch boundaries
//   are cheap (~5us); persistent barriers are not. Reverted to R14 structure.
//   New (all mechanism-understood, low-risk):
//   - elist as u16 (N<=65536), 8-aligned segments, ushort8 16B loads:
//     halves edge-index bytes read by 3 kernels.
//   - Fh stored f16 (R15 proved absmax unchanged): -6.4MB write, -6.4MB read.
//   - dropout masks built in setup_scatter launch (stream hides under
//     LDS-bound scatter blocks); place launch is 196 blocks, exits fast.

constexpr int N = 50000;
constexpr int E = 800000;
constexpr int NBUCK = (N + 255) / 256;    // 196 dst-buckets (256 nodes each)
constexpr int CE = 2048;                  // edges per scatter chunk
constexpr int NEB = (E + CE - 1) / CE;    // 391
constexpr int SLOT = 6208;                // 4096 exp + 5sig(320) + 8-align pad(<=1792)
static_assert(N <= 65536, "u16 packing");
static_assert(N % 16 == 0, "16-row blocks need no bounds checks");

typedef _Float16 f16x8 __attribute__((ext_vector_type(8)));
typedef _Float16 f16x4 __attribute__((ext_vector_type(4)));
typedef _Float16 f16x2 __attribute__((ext_vector_type(2)));
typedef float f32x4 __attribute__((ext_vector_type(4)));
typedef unsigned short u16x8 __attribute__((ext_vector_type(8)));
typedef unsigned short u16x4 __attribute__((ext_vector_type(4)));

constexpr int CONVB = (N * 128 / 8 + 255) / 256;   // 3125 convert blocks
constexpr int MASKB = (N * 128) / (8 * 256);       // 3125 blocks per mask

// ---------------- merged setup + scatter + masks ---------------------------
// blocks [0, NEB): edge chunk counting-sort -> bucket slabs of T
// [NEB, +CONVB): x f32 -> HA f16 | +128 wf0 | +128 wf1 | +64 wfZ
// [.., +2*MASKB): dropout bit-masks.
// Wf[((ct*KB+kb)*64+lane)*8+j] = Wcat[ct*16+(lane&15)][kb*32+(lane>>4)*8+j]
__device__ inline void wfrag_build(int idx, int KB, const float* wl,
                                   const float* wr, _Float16* wf) {
  int j = idx & 7;
  int lane = (idx >> 3) & 63;
  int kb = (idx >> 9) % KB;
  int ct = (idx >> 9) / KB;
  int c = ct * 16 + (lane & 15);
  int k = kb * 32 + (lane >> 4) * 8 + j;
  float v = (k < 128) ? wl[c * 128 + k] : wr[c * 128 + (k - 128)];
  wf[idx] = (_Float16)v;
}

__global__ __launch_bounds__(256) void setup_scatter_kernel(
    const int* __restrict__ src, const int* __restrict__ dst,
    int* __restrict__ bcur, unsigned* __restrict__ T,
    const float* __restrict__ x,
    const float* __restrict__ u1, const float* __restrict__ u2,
    const float* __restrict__ wl0, const float* __restrict__ wr0,
    const float* __restrict__ wl1, const float* __restrict__ wr1,
    const float* __restrict__ wl2, const float* __restrict__ wr2,
    _Float16* __restrict__ HA, _Float16* __restrict__ wf0,
    _Float16* __restrict__ wf1, _Float16* __restrict__ wfZ,
    unsigned* __restrict__ mk1, unsigned* __restrict__ mk2) {
  __shared__ unsigned sorted[CE];
  __shared__ int hist[256], scan[256], excl[256], lcur[256], gbase[256];
  const int b = blockIdx.x;
  const int t = threadIdx.x;
  if (b < NEB) {                          // ---- scatter branch ----
    const int e0 = b * CE;
    const int nval = min(CE, E - e0);
    hist[t] = 0;
    __syncthreads();
    for (int i = t; i < nval; i += 256) atomicAdd(&hist[dst[e0 + i] >> 8], 1);
    __syncthreads();
    const int h = hist[t];
    scan[t] = h;
    __syncthreads();
    for (int off = 1; off < 256; off <<= 1) {
      int u = (t >= off) ? scan[t - off] : 0;
      __syncthreads();
      scan[t] += u;
      __syncthreads();
    }
    excl[t] = scan[t] - h;
    lcur[t] = scan[t] - h;
    gbase[t] = (t < NBUCK && h > 0) ? (t * SLOT + atomicAdd(&bcur[t], h)) : 0;
    __syncthreads();
    for (int i = t; i < nval; i += 256) {
      int e = e0 + i;
      int d = dst[e];
      int p = atomicAdd(&lcur[d >> 8], 1);
      sorted[p] = ((unsigned)d << 16) | (unsigned)src[e];
    }
    __syncthreads();
    for (int i = t; i < nval; i += 256) {
      unsigned pk = sorted[i];
      int bb = pk >> 24;                  // == dst>>8
      T[gbase[bb] + (i - excl[bb])] = pk;
    }
    return;
  }
  const int b2 = b - NEB;
  if (b2 < CONVB) {                       // ---- convert branch ----
    int i = b2 * 256 + t;                 // one thread per 8 elems
    if (i < N * 128 / 8) {
      float4 a = ((const float4*)x)[i * 2];
      float4 c = ((const float4*)x)[i * 2 + 1];
      f16x8 v;
      v[0] = (_Float16)a.x; v[1] = (_Float16)a.y; v[2] = (_Float16)a.z; v[3] = (_Float16)a.w;
      v[4] = (_Float16)c.x; v[5] = (_Float16)c.y; v[6] = (_Float16)c.z; v[7] = (_Float16)c.w;
      ((f16x8*)HA)[i] = v;
    }
  } else if (b2 < CONVB + 128) {          // wf0: [wl0|wr0], K=256
    wfrag_build((b2 - CONVB) * 256 + t, 8, wl0, wr0, wf0);
  } else if (b2 < CONVB + 256) {          // wf1: [wl1|wr1]
    wfrag_build((b2 - CONVB - 128) * 256 + t, 8, wl1, wr1, wf1);
  } else if (b2 < CONVB + 320) {          // wfZ: 8ct*4kb*512 = 16384 = 64 blk
    int idx = (b2 - CONVB - 256) * 256 + t;
    int j = idx & 7;
    int lane = (idx >> 3) & 63;
    int kb = (idx >> 9) & 3;
    int ct = idx >> 11;                   // 0..7
    int c = ct * 16 + (lane & 15);
    int k = kb * 32 + (lane >> 4) * 8 + j;
    float v = (c < 64) ? wl2[c * 128 + k] : wr2[(c - 64) * 128 + k];
    wfZ[idx] = (_Float16)v;
  } else {                                // ---- mask branch ----
    int mb = b2 - (CONVB + 320);
    const float* Us = (mb < MASKB) ? u1 : u2;
    unsigned* MKs = (mb < MASKB) ? mk1 : mk2;
    int bb = (mb < MASKB) ? mb : (mb - MASKB);
#pragma unroll
    for (int k = 0; k < 8; ++k) {
      int i = (bb * 8 + k) * 256 + t;     // wave covers 64 consecutive elems
      unsigned long long m = __ballot(Us[i] >= 0.3f);
      int lt = t & 63;
      if (lt == 0) MKs[i >> 5] = (unsigned)m;
      else if (lt == 32) MKs[i >> 5] = (unsigned)(m >> 32);
    }
  }
}

// Phase B: one block per bucket; offsets/degrees with 8-ALIGNED segments
// (u16 elist, ushort8 loads need e0%8==0), place edges as u16.
__global__ __launch_bounds__(256) void bucket_place_kernel(
    const unsigned* __restrict__ T, const int* __restrict__ bcur,
    int* __restrict__ offs, int* __restrict__ deg,
    unsigned short* __restrict__ elist) {
  __shared__ int dcnt[256], s[256], ncur[256];
  const int t = threadIdx.x;
  const int b = blockIdx.x;
  const int lo = b * SLOT;
  const int hi = lo + bcur[b];            // bcur holds per-bucket edge count
  dcnt[t] = 0;
  __syncthreads();
  for (int i = lo + t; i < hi; i += 256) atomicAdd(&dcnt[(T[i] >> 16) & 255], 1);
  __syncthreads();
  const int v = dcnt[t];
  const int pv = (v + 7) & ~7;            // 8-aligned segment length
  s[t] = pv;
  __syncthreads();
  for (int off = 1; off < 256; off <<= 1) {
    int u = (t >= off) ? s[t - off] : 0;
    __syncthreads();
    s[t] += u;
    __syncthreads();
  }
  const int base = lo + s[t] - pv;        // within-bucket exclusive + slab base
  const int node = b * 256 + t;
  if (node < N) { offs[node] = base; deg[node] = v; }
  ncur[t] = base;
  __syncthreads();
  for (int i = lo + t; i < hi; i += 256) {
    unsigned pk = T[i];
    int pos = atomicAdd(&ncur[(pk >> 16) & 255], 1);
    elist[pos] = (unsigned short)(pk & 0xffffu);
  }
}

// ---------------- fused layer 0: gather-mean -> LDS frags -> MFMA GEMM ----
__global__ __launch_bounds__(256, 8) void fused_layer_kernel(
    const _Float16* __restrict__ H, const int* __restrict__ offs,
    const int* __restrict__ deg, const unsigned short* __restrict__ elist,
    const _Float16* __restrict__ Wf, const float* __restrict__ bias,
    const unsigned* __restrict__ MK, _Float16* __restrict__ outp) {
  __shared__ __align__(16) _Float16 Af[8][64][8];      // [kb][lane][j] 8 KB
  const int t = threadIdx.x;
  const int rowbase = blockIdx.x * 16;

  // phase 1a: own H rows -> Af[4..7]
  {
    int r = t >> 4, o = t & 15;           // r: 0..15 row, o: 0..15 octet
    f16x8 v = *(const f16x8*)(H + (size_t)(rowbase + r) * 128 + o * 8);
    *(f16x8*)&Af[4 + (o >> 2)][(o & 3) * 16 + r][0] = v;
  }

  // phase 1b: gather-mean -> Af[0..3]; half-wave (32 lanes) per node
  {
    const int hw = t >> 5;                // 0..7
    const int ll = t & 31;                // cols 4*ll .. 4*ll+3
    const int kb = ll >> 3, q = (ll >> 1) & 3, j = (ll & 1) * 4;
#pragma unroll 1
    for (int i = 0; i < 2; ++i) {
      int r = hw * 2 + i;
      int node = rowbase + r;
      float a0 = 0.f, a1 = 0.f, a2 = 0.f, a3 = 0.f;
      const int e0 = offs[node];          // e0 % 8 == 0 (padded scan)
      const int d = deg[node];
      const int e1 = e0 + d;
      int e = e0;
      for (; e + 16 <= e1; e += 16) {
        u16x8 q0 = *(const u16x8*)(elist + e);
        u16x8 q1 = *(const u16x8*)(elist + e + 8);
        int s[16] = {q0[0], q0[1], q0[2], q0[3], q0[4], q0[5], q0[6], q0[7],
                     q1[0], q1[1], q1[2], q1[3], q1[4], q1[5], q1[6], q1[7]};
        f16x4 v[16];
#pragma unroll
        for (int u = 0; u < 16; ++u)
          v[u] = *(const f16x4*)(H + (size_t)s[u] * 128 + ll * 4);
#pragma unroll
        for (int u = 0; u < 16; ++u) {
          a0 += (float)v[u][0]; a1 += (float)v[u][1];
          a2 += (float)v[u][2]; a3 += (float)v[u][3];
        }
      }
      for (; e + 4 <= e1; e += 4) {
        u16x4 q4 = *(const u16x4*)(elist + e);
        int s[4] = {q4[0], q4[1], q4[2], q4[3]};
        f16x4 v[4];
#pragma unroll
        for (int u = 0; u < 4; ++u)
          v[u] = *(const f16x4*)(H + (size_t)s[u] * 128 + ll * 4);
#pragma unroll
        for (int u = 0; u < 4; ++u) {
          a0 += (float)v[u][0]; a1 += (float)v[u][1];
          a2 += (float)v[u][2]; a3 += (float)v[u][3];
        }
      }
      for (; e < e1; ++e) {
        f16x4 v = *(const f16x4*)(H + (size_t)elist[e] * 128 + ll * 4);
        a0 += (float)v[0]; a1 += (float)v[1];
        a2 += (float)v[2]; a3 += (float)v[3];
      }
      float inv = 1.0f / (float)max(d, 1);
      f16x4 o;
      o[0] = (_Float16)(a0 * inv); o[1] = (_Float16)(a1 * inv);
      o[2] = (_Float16)(a2 * inv); o[3] = (_Float16)(a3 * inv);
      *(f16x4*)&Af[kb][q * 16 + r][j] = o;
    }
  }
  __syncthreads();

  // phase 2: GEMM. Wave w covers cols w*32..w*32+31; 16 rows.
  const int lane = t & 63;
  const int w = t >> 6;
  const int n16 = lane & 15;
  const int qq = lane >> 4;
  const int colbase = w * 32;

  f32x4 acc[2];
  acc[0] = (f32x4){0.f, 0.f, 0.f, 0.f};
  acc[1] = (f32x4){0.f, 0.f, 0.f, 0.f};

#pragma unroll
  for (int kb = 0; kb < 8; ++kb) {
    f16x8 a = *(const f16x8*)&Af[kb][lane][0];
#pragma unroll
    for (int ct = 0; ct < 2; ++ct) {
      const int ctg = w * 2 + ct;
      f16x8 b = *(const f16x8*)(Wf + ((size_t)(ctg * 8 + kb) * 64 + lane) * 8);
      acc[ct] = __builtin_amdgcn_mfma_f32_16x16x32_f16(a, b, acc[ct], 0, 0, 0);
    }
  }

  // C/D layout: col = lane&15, row = (lane>>4)*4 + reg
#pragma unroll
  for (int r = 0; r < 4; ++r) {
    int row = rowbase + qq * 4 + r;
    unsigned mw = MK[(size_t)row * 4 + w];
#pragma unroll
    for (int ct = 0; ct < 2; ++ct) {
      const int col = colbase + ct * 16 + n16;
      float v = fmaxf(acc[ct][r] + bias[col], 0.f);
      v = ((mw >> (ct * 16 + n16)) & 1u) ? v * (1.0f / 0.7f) : 0.0f;
      outp[(size_t)row * 128 + col] = (_Float16)v;
    }
  }
}

// ---------------- fused layer 1 + layer-2 GEMM ----------------------------
// h1 never hits global: epilogue -> Zf LDS, sync, layer-2 GEMM vs wfZ
// -> Y2 (f16) + Fh (f16).
__global__ __launch_bounds__(256, 8) void fused_layerZ_kernel(
    const _Float16* __restrict__ H, const int* __restrict__ offs,
    const int* __restrict__ deg, const unsigned short* __restrict__ elist,
    const _Float16* __restrict__ Wf, const float* __restrict__ bias,
    const unsigned* __restrict__ MK, const _Float16* __restrict__ WfZ,
    const float* __restrict__ bl2, _Float16* __restrict__ Y2,
    _Float16* __restrict__ Fh) {
  __shared__ __align__(16) _Float16 Af[8][64][8];      // 8 KB
  __shared__ __align__(16) _Float16 Zf[16][136];       // 4.25 KB
  const int t = threadIdx.x;
  const int rowbase = blockIdx.x * 16;

  {
    int r = t >> 4, o = t & 15;
    f16x8 v = *(const f16x8*)(H + (size_t)(rowbase + r) * 128 + o * 8);
    *(f16x8*)&Af[4 + (o >> 2)][(o & 3) * 16 + r][0] = v;
  }

  {
    const int hw = t >> 5;
    const int ll = t & 31;
    const int kb = ll >> 3, q = (ll >> 1) & 3, j = (ll & 1) * 4;
#pragma unroll 1
    for (int i = 0; i < 2; ++i) {
      int r = hw * 2 + i;
      int node = rowbase + r;
      float a0 = 0.f, a1 = 0.f, a2 = 0.f, a3 = 0.f;
      const int e0 = offs[node];
      const int d = deg[node];
      const int e1 = e0 + d;
      int e = e0;
      for (; e + 16 <= e1; e += 16) {
        u16x8 q0 = *(const u16x8*)(elist + e);
        u16x8 q1 = *(const u16x8*)(elist + e + 8);
        int s[16] = {q0[0], q0[1], q0[2], q0[3], q0[4], q0[5], q0[6], q0[7],
                     q1[0], q1[1], q1[2], q1[3], q1[4], q1[5], q1[6], q1[7]};
        f16x4 v[16];
#pragma unroll
        for (int u = 0; u < 16; ++u)
          v[u] = *(const f16x4*)(H + (size_t)s[u] * 128 + ll * 4);
#pragma unroll
        for (int u = 0; u < 16; ++u) {
          a0 += (float)v[u][0]; a1 += (float)v[u][1];
          a2 += (float)v[u][2]; a3 += (float)v[u][3];
        }
      }
      for (; e + 4 <= e1; e += 4) {
        u16x4 q4 = *(const u16x4*)(elist + e);
        int s[4] = {q4[0], q4[1], q4[2], q4[3]};
        f16x4 v[4];
#pragma unroll
        for (int u = 0; u < 4; ++u)
          v[u] = *(const f16x4*)(H + (size_t)s[u] * 128 + ll * 4);
#pragma unroll
        for (int u = 0; u < 4; ++u) {
          a0 += (float)v[u][0]; a1 += (float)v[u][1];
          a2 += (float)v[u][2]; a3 += (float)v[u][3];
        }
      }
      for (; e < e1; ++e) {
        f16x4 v = *(const f16x4*)(H + (size_t)elist[e] * 128 + ll * 4);
        a0 += (float)v[0]; a1 += (float)v[1];
        a2 += (float)v[2]; a3 += (float)v[3];
      }
      float inv = 1.0f / (float)max(d, 1);
      f16x4 o;
      o[0] = (_Float16)(a0 * inv); o[1] = (_Float16)(a1 * inv);
      o[2] = (_Float16)(a2 * inv); o[3] = (_Float16)(a3 * inv);
      *(f16x4*)&Af[kb][q * 16 + r][j] = o;
    }
  }
  __syncthreads();

  const int lane = t & 63;
  const int w = t >> 6;
  const int n16 = lane & 15;
  const int qq = lane >> 4;
  const int colbase = w * 32;

  f32x4 acc[2];
  acc[0] = (f32x4){0.f, 0.f, 0.f, 0.f};
  acc[1] = (f32x4){0.f, 0.f, 0.f, 0.f};

#pragma unroll
  for (int kb = 0; kb < 8; ++kb) {
    f16x8 a = *(const f16x8*)&Af[kb][lane][0];
#pragma unroll
    for (int ct = 0; ct < 2; ++ct) {
      const int ctg = w * 2 + ct;
      f16x8 b = *(const f16x8*)(Wf + ((size_t)(ctg * 8 + kb) * 64 + lane) * 8);
      acc[ct] = __builtin_amdgcn_mfma_f32_16x16x32_f16(a, b, acc[ct], 0, 0, 0);
    }
  }

  // epilogue: h1 = dropout(relu(acc+bias)) -> Zf
#pragma unroll
  for (int r = 0; r < 4; ++r) {
    int row = qq * 4 + r;                 // local 0..15
    unsigned mw = MK[(size_t)(rowbase + row) * 4 + w];
#pragma unroll
    for (int ct = 0; ct < 2; ++ct) {
      const int col = colbase + ct * 16 + n16;
      float v = fmaxf(acc[ct][r] + bias[col], 0.f);
      v = ((mw >> (ct * 16 + n16)) & 1u) ? v * (1.0f / 0.7f) : 0.0f;
      Zf[row][col] = (_Float16)v;
    }
  }
  __syncthreads();

  // layer-2 GEMM: A = Zf rows (K=128), B = WfZ
  f32x4 az[2];
  az[0] = (f32x4){0.f, 0.f, 0.f, 0.f};
  az[1] = (f32x4){0.f, 0.f, 0.f, 0.f};
#pragma unroll
  for (int kb = 0; kb < 4; ++kb) {
    f16x8 a = *(const f16x8*)&Zf[n16][kb * 32 + qq * 8];
#pragma unroll
    for (int ct = 0; ct < 2; ++ct) {
      const int ctg = w * 2 + ct;
      f16x8 b = *(const f16x8*)(WfZ + ((size_t)(ctg * 4 + kb) * 64 + lane) * 8);
      az[ct] = __builtin_amdgcn_mfma_f32_16x16x32_f16(a, b, az[ct], 0, 0, 0);
    }
  }
#pragma unroll
  for (int ct = 0; ct < 2; ++ct) {
    const int col = colbase + ct * 16 + n16;   // 0..127
#pragma unroll
    for (int r = 0; r < 4; ++r) {
      int row = rowbase + qq * 4 + r;
      float v = az[ct][r];
      if (col < 64) Y2[(size_t)row * 64 + col] = (_Float16)v;
      else Fh[(size_t)row * 64 + (col - 64)] = (_Float16)(v + bl2[col - 64]);
    }
  }
}

// ---------------- gather64 + final add: out = Fh + mean(Y2[nbrs]) ---------
__global__ __launch_bounds__(256) void gather64_add_kernel(
    const _Float16* __restrict__ Y2, const _Float16* __restrict__ Fh,
    const int* __restrict__ offs, const int* __restrict__ deg,
    const unsigned short* __restrict__ elist, float* __restrict__ out) {
  int node = blockIdx.x * 8 + (threadIdx.x >> 5);
  if (node >= N) return;
  int l = threadIdx.x & 31;
  const int e0 = offs[node];              // e0 % 8 == 0
  const int d = deg[node];
  const int e1 = e0 + d;
  float a0 = 0.f, a1 = 0.f;
  int e = e0;
  for (; e + 16 <= e1; e += 16) {
    u16x8 q0 = *(const u16x8*)(elist + e);
    u16x8 q1 = *(const u16x8*)(elist + e + 8);
    int s[16] = {q0[0], q0[1], q0[2], q0[3], q0[4], q0[5], q0[6], q0[7],
                 q1[0], q1[1], q1[2], q1[3], q1[4], q1[5], q1[6], q1[7]};
    f16x2 v[16];
#pragma unroll
    for (int u = 0; u < 16; ++u)
      v[u] = *(const f16x2*)(Y2 + (size_t)s[u] * 64 + l * 2);
#pragma unroll
    for (int u = 0; u < 16; ++u) { a0 += (float)v[u][0]; a1 += (float)v[u][1]; }
  }
  for (; e + 4 <= e1; e += 4) {
    u16x4 q = *(const u16x4*)(elist + e);
    int s[4] = {q[0], q[1], q[2], q[3]};
    f16x2 v[4];
#pragma unroll
    for (int u = 0; u < 4; ++u)
      v[u] = *(const f16x2*)(Y2 + (size_t)s[u] * 64 + l * 2);
#pragma unroll
    for (int u = 0; u < 4; ++u) { a0 += (float)v[u][0]; a1 += (float)v[u][1]; }
  }
  for (; e < e1; ++e) {
    f16x2 v = *(const f16x2*)(Y2 + (size_t)elist[e] * 64 + l * 2);
    a0 += (float)v[0]; a1 += (float)v[1];
  }
  float inv = 1.0f / (float)max(d, 1);
  f16x2 fv = ((const f16x2*)(Fh + (size_t)node * 64))[l];
  float2 o;
  o.x = (float)fv[0] + a0 * inv;
  o.y = (float)fv[1] + a1 * inv;
  ((float2*)(out + (size_t)node * 64))[l] = o;
}

extern "C" void kernel_launch(void* const* d_in, const int* in_sizes, int n_in,
                              void* d_out, int out_size, void* d_ws, size_t ws_size,
                              hipStream_t stream) {
  const float* x   = (const float*)d_in[0];
  const float* u1  = (const float*)d_in[1];
  const float* u2  = (const float*)d_in[2];
  const float* wl0 = (const float*)d_in[3];
  const float* bl0 = (const float*)d_in[4];
  const float* wr0 = (const float*)d_in[5];
  const float* wl1 = (const float*)d_in[6];
  const float* bl1 = (const float*)d_in[7];
  const float* wr1 = (const float*)d_in[8];
  const float* wl2 = (const float*)d_in[9];
  const float* bl2 = (const float*)d_in[10];
  const float* wr2 = (const float*)d_in[11];
  const int* edge  = (const int*)d_in[12];
  const int* src = edge;
  const int* dst = edge + E;

  // workspace layout
  _Float16* HA  = (_Float16*)d_ws;                 // N x 128 f16
  _Float16* HB  = HA + (size_t)N * 128;            // N x 128 f16
  _Float16* Y2  = HB + (size_t)N * 128;            // N x 64 f16
  _Float16* Fh  = Y2 + (size_t)N * 64;             // N x 64 f16
  int* offs     = (int*)(Fh + (size_t)N * 64);     // N
  int* deg      = offs + N;                        // N
  unsigned short* elist = (unsigned short*)(deg + N);  // NBUCK*SLOT u16
  unsigned* T   = (unsigned*)(elist + NBUCK * SLOT);   // NBUCK*SLOT u32
  int* bcur     = (int*)(T + NBUCK * SLOT);        // NBUCK (counts)
  uintptr_t p = (uintptr_t)(bcur + NBUCK);
  p = (p + 15) & ~(uintptr_t)15;
  _Float16* wf0 = (_Float16*)p;                    // 8*8*512
  _Float16* wf1 = wf0 + 8 * 8 * 512;
  _Float16* wfZ = wf1 + 8 * 8 * 512;               // 8*4*512
  unsigned* mk1 = (unsigned*)(wfZ + 8 * 4 * 512);  // N*4 u32 (bit mask)
  unsigned* mk2 = mk1 + (size_t)N * 4;             // N*4 u32

  // 0) bcur counts = 0
  hipMemsetAsync(bcur, 0, NBUCK * sizeof(int), stream);
  // 1) merged setup + scatter + masks
  setup_scatter_kernel<<<NEB + CONVB + 320 + 2 * MASKB, 256, 0, stream>>>(
      src, dst, bcur, T, x, u1, u2, wl0, wr0, wl1, wr1, wl2, wr2,
      HA, wf0, wf1, wfZ, mk1, mk2);
  // 2) place
  bucket_place_kernel<<<NBUCK, 256, 0, stream>>>(T, bcur, offs, deg, elist);

  const int GM16 = N / 16;             // 3125 fused-layer blocks
  const int GG64 = (N + 7) / 8;        // half-wave per node

  // ---- Layer 0 (fused gather+GEMM) ----
  fused_layer_kernel<<<GM16, 256, 0, stream>>>(HA, offs, deg, elist, wf0, bl0,
                                               mk1, HB);
  // ---- Layer 1 + Layer-2 GEMM (fused; h1 never hits global) ----
  fused_layerZ_kernel<<<GM16, 256, 0, stream>>>(HB, offs, deg, elist, wf1, bl1,
                                                mk2, wfZ, bl2, Y2, Fh);
  // ---- Layer 2 gather + add ----
  gather64_add_kernel<<<GG64, 256, 0, stream>>>(Y2, Fh, offs, deg, elist,
                                                (float*)d_out);
}

// Round 8
// 265.462 us; speedup vs baseline: 4.6571x; 1.0304x over previous
//
#include <hip/hip_runtime.h>

// GraphSAGE 3-layer forward, MI355X. Round 17:
//   R16 post-mortem: Fh f16 scattered 2B stores caused partial-sector RMW
//   (WRITE_SIZE 22.6->28.4MB, layerZ 50->53us). Revert F to f32. Keep u16
//   elist (byte win) + masks-in-setup_scatter. New: CE 2048->4096 (halves
//   scatter scan/atomic fixed cost; the other ~9.5K blocks in the merged
//   launch supply occupancy). Fused-layer gather structure untouched
//   (fabric-throughput-bound at ~4.8 TB/s effective).

constexpr int N = 50000;
constexpr int E = 800000;
constexpr int NBUCK = (N + 255) / 256;    // 196 dst-buckets (256 nodes each)
constexpr int CE = 4096;                  // edges per scatter chunk
constexpr int NEB = (E + CE - 1) / CE;    // 196
constexpr int SLOT = 6208;                // 4096 exp + sigma + 8-align pad
static_assert(N <= 65536, "u16 packing");
static_assert(N % 16 == 0, "16-row blocks need no bounds checks");

typedef _Float16 f16x8 __attribute__((ext_vector_type(8)));
typedef _Float16 f16x4 __attribute__((ext_vector_type(4)));
typedef _Float16 f16x2 __attribute__((ext_vector_type(2)));
typedef float f32x4 __attribute__((ext_vector_type(4)));
typedef unsigned short u16x8 __attribute__((ext_vector_type(8)));
typedef unsigned short u16x4 __attribute__((ext_vector_type(4)));

constexpr int CONVB = (N * 128 / 8 + 255) / 256;   // 3125 convert blocks
constexpr int MASKB = (N * 128) / (8 * 256);       // 3125 blocks per mask

// ---------------- merged setup + scatter + masks ---------------------------
// blocks [0, NEB): edge chunk counting-sort -> bucket slabs of T
// [NEB, +CONVB): x f32 -> HA f16 | +128 wf0 | +128 wf1 | +64 wfZ
// [.., +2*MASKB): dropout bit-masks.
// Wf[((ct*KB+kb)*64+lane)*8+j] = Wcat[ct*16+(lane&15)][kb*32+(lane>>4)*8+j]
__device__ inline void wfrag_build(int idx, int KB, const float* wl,
                                   const float* wr, _Float16* wf) {
  int j = idx & 7;
  int lane = (idx >> 3) & 63;
  int kb = (idx >> 9) % KB;
  int ct = (idx >> 9) / KB;
  int c = ct * 16 + (lane & 15);
  int k = kb * 32 + (lane >> 4) * 8 + j;
  float v = (k < 128) ? wl[c * 128 + k] : wr[c * 128 + (k - 128)];
  wf[idx] = (_Float16)v;
}

__global__ __launch_bounds__(256) void setup_scatter_kernel(
    const int* __restrict__ src, const int* __restrict__ dst,
    int* __restrict__ bcur, unsigned* __restrict__ T,
    const float* __restrict__ x,
    const float* __restrict__ u1, const float* __restrict__ u2,
    const float* __restrict__ wl0, const float* __restrict__ wr0,
    const float* __restrict__ wl1, const float* __restrict__ wr1,
    const float* __restrict__ wl2, const float* __restrict__ wr2,
    _Float16* __restrict__ HA, _Float16* __restrict__ wf0,
    _Float16* __restrict__ wf1, _Float16* __restrict__ wfZ,
    unsigned* __restrict__ mk1, unsigned* __restrict__ mk2) {
  __shared__ unsigned sorted[CE];
  __shared__ int hist[256], scan[256], excl[256], lcur[256], gbase[256];
  const int b = blockIdx.x;
  const int t = threadIdx.x;
  if (b < NEB) {                          // ---- scatter branch ----
    const int e0 = b * CE;
    const int nval = min(CE, E - e0);
    hist[t] = 0;
    __syncthreads();
    for (int i = t; i < nval; i += 256) atomicAdd(&hist[dst[e0 + i] >> 8], 1);
    __syncthreads();
    const int h = hist[t];
    scan[t] = h;
    __syncthreads();
    for (int off = 1; off < 256; off <<= 1) {
      int u = (t >= off) ? scan[t - off] : 0;
      __syncthreads();
      scan[t] += u;
      __syncthreads();
    }
    excl[t] = scan[t] - h;
    lcur[t] = scan[t] - h;
    gbase[t] = (t < NBUCK && h > 0) ? (t * SLOT + atomicAdd(&bcur[t], h)) : 0;
    __syncthreads();
    for (int i = t; i < nval; i += 256) {
      int e = e0 + i;
      int d = dst[e];
      int p = atomicAdd(&lcur[d >> 8], 1);
      sorted[p] = ((unsigned)d << 16) | (unsigned)src[e];
    }
    __syncthreads();
    for (int i = t; i < nval; i += 256) {
      unsigned pk = sorted[i];
      int bb = pk >> 24;                  // == dst>>8
      T[gbase[bb] + (i - excl[bb])] = pk;
    }
    return;
  }
  const int b2 = b - NEB;
  if (b2 < CONVB) {                       // ---- convert branch ----
    int i = b2 * 256 + t;                 // one thread per 8 elems
    if (i < N * 128 / 8) {
      float4 a = ((const float4*)x)[i * 2];
      float4 c = ((const float4*)x)[i * 2 + 1];
      f16x8 v;
      v[0] = (_Float16)a.x; v[1] = (_Float16)a.y; v[2] = (_Float16)a.z; v[3] = (_Float16)a.w;
      v[4] = (_Float16)c.x; v[5] = (_Float16)c.y; v[6] = (_Float16)c.z; v[7] = (_Float16)c.w;
      ((f16x8*)HA)[i] = v;
    }
  } else if (b2 < CONVB + 128) {          // wf0: [wl0|wr0], K=256
    wfrag_build((b2 - CONVB) * 256 + t, 8, wl0, wr0, wf0);
  } else if (b2 < CONVB + 256) {          // wf1: [wl1|wr1]
    wfrag_build((b2 - CONVB - 128) * 256 + t, 8, wl1, wr1, wf1);
  } else if (b2 < CONVB + 320) {          // wfZ: 8ct*4kb*512 = 16384 = 64 blk
    int idx = (b2 - CONVB - 256) * 256 + t;
    int j = idx & 7;
    int lane = (idx >> 3) & 63;
    int kb = (idx >> 9) & 3;
    int ct = idx >> 11;                   // 0..7
    int c = ct * 16 + (lane & 15);
    int k = kb * 32 + (lane >> 4) * 8 + j;
    float v = (c < 64) ? wl2[c * 128 + k] : wr2[(c - 64) * 128 + k];
    wfZ[idx] = (_Float16)v;
  } else {                                // ---- mask branch ----
    int mb = b2 - (CONVB + 320);
    const float* Us = (mb < MASKB) ? u1 : u2;
    unsigned* MKs = (mb < MASKB) ? mk1 : mk2;
    int bb = (mb < MASKB) ? mb : (mb - MASKB);
#pragma unroll
    for (int k = 0; k < 8; ++k) {
      int i = (bb * 8 + k) * 256 + t;     // wave covers 64 consecutive elems
      unsigned long long m = __ballot(Us[i] >= 0.3f);
      int lt = t & 63;
      if (lt == 0) MKs[i >> 5] = (unsigned)m;
      else if (lt == 32) MKs[i >> 5] = (unsigned)(m >> 32);
    }
  }
}

// Phase B: one block per bucket; offsets/degrees with 8-ALIGNED segments
// (u16 elist, ushort8 loads need e0%8==0), place edges as u16.
__global__ __launch_bounds__(256) void bucket_place_kernel(
    const unsigned* __restrict__ T, const int* __restrict__ bcur,
    int* __restrict__ offs, int* __restrict__ deg,
    unsigned short* __restrict__ elist) {
  __shared__ int dcnt[256], s[256], ncur[256];
  const int t = threadIdx.x;
  const int b = blockIdx.x;
  const int lo = b * SLOT;
  const int hi = lo + bcur[b];            // bcur holds per-bucket edge count
  dcnt[t] = 0;
  __syncthreads();
  for (int i = lo + t; i < hi; i += 256) atomicAdd(&dcnt[(T[i] >> 16) & 255], 1);
  __syncthreads();
  const int v = dcnt[t];
  const int pv = (v + 7) & ~7;            // 8-aligned segment length
  s[t] = pv;
  __syncthreads();
  for (int off = 1; off < 256; off <<= 1) {
    int u = (t >= off) ? s[t - off] : 0;
    __syncthreads();
    s[t] += u;
    __syncthreads();
  }
  const int base = lo + s[t] - pv;        // within-bucket exclusive + slab base
  const int node = b * 256 + t;
  if (node < N) { offs[node] = base; deg[node] = v; }
  ncur[t] = base;
  __syncthreads();
  for (int i = lo + t; i < hi; i += 256) {
    unsigned pk = T[i];
    int pos = atomicAdd(&ncur[(pk >> 16) & 255], 1);
    elist[pos] = (unsigned short)(pk & 0xffffu);
  }
}

// ---------------- fused layer 0: gather-mean -> LDS frags -> MFMA GEMM ----
__global__ __launch_bounds__(256, 8) void fused_layer_kernel(
    const _Float16* __restrict__ H, const int* __restrict__ offs,
    const int* __restrict__ deg, const unsigned short* __restrict__ elist,
    const _Float16* __restrict__ Wf, const float* __restrict__ bias,
    const unsigned* __restrict__ MK, _Float16* __restrict__ outp) {
  __shared__ __align__(16) _Float16 Af[8][64][8];      // [kb][lane][j] 8 KB
  const int t = threadIdx.x;
  const int rowbase = blockIdx.x * 16;

  // phase 1a: own H rows -> Af[4..7]
  {
    int r = t >> 4, o = t & 15;           // r: 0..15 row, o: 0..15 octet
    f16x8 v = *(const f16x8*)(H + (size_t)(rowbase + r) * 128 + o * 8);
    *(f16x8*)&Af[4 + (o >> 2)][(o & 3) * 16 + r][0] = v;
  }

  // phase 1b: gather-mean -> Af[0..3]; half-wave (32 lanes) per node
  {
    const int hw = t >> 5;                // 0..7
    const int ll = t & 31;                // cols 4*ll .. 4*ll+3
    const int kb = ll >> 3, q = (ll >> 1) & 3, j = (ll & 1) * 4;
#pragma unroll 1
    for (int i = 0; i < 2; ++i) {
      int r = hw * 2 + i;
      int node = rowbase + r;
      float a0 = 0.f, a1 = 0.f, a2 = 0.f, a3 = 0.f;
      const int e0 = offs[node];          // e0 % 8 == 0 (padded scan)
      const int d = deg[node];
      const int e1 = e0 + d;
      int e = e0;
      for (; e + 16 <= e1; e += 16) {
        u16x8 q0 = *(const u16x8*)(elist + e);
        u16x8 q1 = *(const u16x8*)(elist + e + 8);
        int s[16] = {q0[0], q0[1], q0[2], q0[3], q0[4], q0[5], q0[6], q0[7],
                     q1[0], q1[1], q1[2], q1[3], q1[4], q1[5], q1[6], q1[7]};
        f16x4 v[16];
#pragma unroll
        for (int u = 0; u < 16; ++u)
          v[u] = *(const f16x4*)(H + (size_t)s[u] * 128 + ll * 4);
#pragma unroll
        for (int u = 0; u < 16; ++u) {
          a0 += (float)v[u][0]; a1 += (float)v[u][1];
          a2 += (float)v[u][2]; a3 += (float)v[u][3];
        }
      }
      for (; e + 4 <= e1; e += 4) {
        u16x4 q4 = *(const u16x4*)(elist + e);
        int s[4] = {q4[0], q4[1], q4[2], q4[3]};
        f16x4 v[4];
#pragma unroll
        for (int u = 0; u < 4; ++u)
          v[u] = *(const f16x4*)(H + (size_t)s[u] * 128 + ll * 4);
#pragma unroll
        for (int u = 0; u < 4; ++u) {
          a0 += (float)v[u][0]; a1 += (float)v[u][1];
          a2 += (float)v[u][2]; a3 += (float)v[u][3];
        }
      }
      for (; e < e1; ++e) {
        f16x4 v = *(const f16x4*)(H + (size_t)elist[e] * 128 + ll * 4);
        a0 += (float)v[0]; a1 += (float)v[1];
        a2 += (float)v[2]; a3 += (float)v[3];
      }
      float inv = 1.0f / (float)max(d, 1);
      f16x4 o;
      o[0] = (_Float16)(a0 * inv); o[1] = (_Float16)(a1 * inv);
      o[2] = (_Float16)(a2 * inv); o[3] = (_Float16)(a3 * inv);
      *(f16x4*)&Af[kb][q * 16 + r][j] = o;
    }
  }
  __syncthreads();

  // phase 2: GEMM. Wave w covers cols w*32..w*32+31; 16 rows.
  const int lane = t & 63;
  const int w = t >> 6;
  const int n16 = lane & 15;
  const int qq = lane >> 4;
  const int colbase = w * 32;

  f32x4 acc[2];
  acc[0] = (f32x4){0.f, 0.f, 0.f, 0.f};
  acc[1] = (f32x4){0.f, 0.f, 0.f, 0.f};

#pragma unroll
  for (int kb = 0; kb < 8; ++kb) {
    f16x8 a = *(const f16x8*)&Af[kb][lane][0];
#pragma unroll
    for (int ct = 0; ct < 2; ++ct) {
      const int ctg = w * 2 + ct;
      f16x8 b = *(const f16x8*)(Wf + ((size_t)(ctg * 8 + kb) * 64 + lane) * 8);
      acc[ct] = __builtin_amdgcn_mfma_f32_16x16x32_f16(a, b, acc[ct], 0, 0, 0);
    }
  }

  // C/D layout: col = lane&15, row = (lane>>4)*4 + reg
#pragma unroll
  for (int r = 0; r < 4; ++r) {
    int row = rowbase + qq * 4 + r;
    unsigned mw = MK[(size_t)row * 4 + w];
#pragma unroll
    for (int ct = 0; ct < 2; ++ct) {
      const int col = colbase + ct * 16 + n16;
      float v = fmaxf(acc[ct][r] + bias[col], 0.f);
      v = ((mw >> (ct * 16 + n16)) & 1u) ? v * (1.0f / 0.7f) : 0.0f;
      outp[(size_t)row * 128 + col] = (_Float16)v;
    }
  }
}

// ---------------- fused layer 1 + layer-2 GEMM ----------------------------
// h1 never hits global: epilogue -> Zf LDS, sync, layer-2 GEMM vs wfZ
// -> Y2 (f16) + F (f32; 4B stores coalesce better than 2B, R16 lesson).
__global__ __launch_bounds__(256, 8) void fused_layerZ_kernel(
    const _Float16* __restrict__ H, const int* __restrict__ offs,
    const int* __restrict__ deg, const unsigned short* __restrict__ elist,
    const _Float16* __restrict__ Wf, const float* __restrict__ bias,
    const unsigned* __restrict__ MK, const _Float16* __restrict__ WfZ,
    const float* __restrict__ bl2, _Float16* __restrict__ Y2,
    float* __restrict__ F) {
  __shared__ __align__(16) _Float16 Af[8][64][8];      // 8 KB
  __shared__ __align__(16) _Float16 Zf[16][136];       // 4.25 KB
  const int t = threadIdx.x;
  const int rowbase = blockIdx.x * 16;

  {
    int r = t >> 4, o = t & 15;
    f16x8 v = *(const f16x8*)(H + (size_t)(rowbase + r) * 128 + o * 8);
    *(f16x8*)&Af[4 + (o >> 2)][(o & 3) * 16 + r][0] = v;
  }

  {
    const int hw = t >> 5;
    const int ll = t & 31;
    const int kb = ll >> 3, q = (ll >> 1) & 3, j = (ll & 1) * 4;
#pragma unroll 1
    for (int i = 0; i < 2; ++i) {
      int r = hw * 2 + i;
      int node = rowbase + r;
      float a0 = 0.f, a1 = 0.f, a2 = 0.f, a3 = 0.f;
      const int e0 = offs[node];
      const int d = deg[node];
      const int e1 = e0 + d;
      int e = e0;
      for (; e + 16 <= e1; e += 16) {
        u16x8 q0 = *(const u16x8*)(elist + e);
        u16x8 q1 = *(const u16x8*)(elist + e + 8);
        int s[16] = {q0[0], q0[1], q0[2], q0[3], q0[4], q0[5], q0[6], q0[7],
                     q1[0], q1[1], q1[2], q1[3], q1[4], q1[5], q1[6], q1[7]};
        f16x4 v[16];
#pragma unroll
        for (int u = 0; u < 16; ++u)
          v[u] = *(const f16x4*)(H + (size_t)s[u] * 128 + ll * 4);
#pragma unroll
        for (int u = 0; u < 16; ++u) {
          a0 += (float)v[u][0]; a1 += (float)v[u][1];
          a2 += (float)v[u][2]; a3 += (float)v[u][3];
        }
      }
      for (; e + 4 <= e1; e += 4) {
        u16x4 q4 = *(const u16x4*)(elist + e);
        int s[4] = {q4[0], q4[1], q4[2], q4[3]};
        f16x4 v[4];
#pragma unroll
        for (int u = 0; u < 4; ++u)
          v[u] = *(const f16x4*)(H + (size_t)s[u] * 128 + ll * 4);
#pragma unroll
        for (int u = 0; u < 4; ++u) {
          a0 += (float)v[u][0]; a1 += (float)v[u][1];
          a2 += (float)v[u][2]; a3 += (float)v[u][3];
        }
      }
      for (; e < e1; ++e) {
        f16x4 v = *(const f16x4*)(H + (size_t)elist[e] * 128 + ll * 4);
        a0 += (float)v[0]; a1 += (float)v[1];
        a2 += (float)v[2]; a3 += (float)v[3];
      }
      float inv = 1.0f / (float)max(d, 1);
      f16x4 o;
      o[0] = (_Float16)(a0 * inv); o[1] = (_Float16)(a1 * inv);
      o[2] = (_Float16)(a2 * inv); o[3] = (_Float16)(a3 * inv);
      *(f16x4*)&Af[kb][q * 16 + r][j] = o;
    }
  }
  __syncthreads();

  const int lane = t & 63;
  const int w = t >> 6;
  const int n16 = lane & 15;
  const int qq = lane >> 4;
  const int colbase = w * 32;

  f32x4 acc[2];
  acc[0] = (f32x4){0.f, 0.f, 0.f, 0.f};
  acc[1] = (f32x4){0.f, 0.f, 0.f, 0.f};

#pragma unroll
  for (int kb = 0; kb < 8; ++kb) {
    f16x8 a = *(const f16x8*)&Af[kb][lane][0];
#pragma unroll
    for (int ct = 0; ct < 2; ++ct) {
      const int ctg = w * 2 + ct;
      f16x8 b = *(const f16x8*)(Wf + ((size_t)(ctg * 8 + kb) * 64 + lane) * 8);
      acc[ct] = __builtin_amdgcn_mfma_f32_16x16x32_f16(a, b, acc[ct], 0, 0, 0);
    }
  }

  // epilogue: h1 = dropout(relu(acc+bias)) -> Zf
#pragma unroll
  for (int r = 0; r < 4; ++r) {
    int row = qq * 4 + r;                 // local 0..15
    unsigned mw = MK[(size_t)(rowbase + row) * 4 + w];
#pragma unroll
    for (int ct = 0; ct < 2; ++ct) {
      const int col = colbase + ct * 16 + n16;
      float v = fmaxf(acc[ct][r] + bias[col], 0.f);
      v = ((mw >> (ct * 16 + n16)) & 1u) ? v * (1.0f / 0.7f) : 0.0f;
      Zf[row][col] = (_Float16)v;
    }
  }
  __syncthreads();

  // layer-2 GEMM: A = Zf rows (K=128), B = WfZ
  f32x4 az[2];
  az[0] = (f32x4){0.f, 0.f, 0.f, 0.f};
  az[1] = (f32x4){0.f, 0.f, 0.f, 0.f};
#pragma unroll
  for (int kb = 0; kb < 4; ++kb) {
    f16x8 a = *(const f16x8*)&Zf[n16][kb * 32 + qq * 8];
#pragma unroll
    for (int ct = 0; ct < 2; ++ct) {
      const int ctg = w * 2 + ct;
      f16x8 b = *(const f16x8*)(WfZ + ((size_t)(ctg * 4 + kb) * 64 + lane) * 8);
      az[ct] = __builtin_amdgcn_mfma_f32_16x16x32_f16(a, b, az[ct], 0, 0, 0);
    }
  }
#pragma unroll
  for (int ct = 0; ct < 2; ++ct) {
    const int col = colbase + ct * 16 + n16;   // 0..127
#pragma unroll
    for (int r = 0; r < 4; ++r) {
      int row = rowbase + qq * 4 + r;
      float v = az[ct][r];
      if (col < 64) Y2[(size_t)row * 64 + col] = (_Float16)v;
      else F[(size_t)row * 64 + (col - 64)] = v + bl2[col - 64];
    }
  }
}

// ---------------- gather64 + final add: out = F + mean(Y2[nbrs]) ----------
__global__ __launch_bounds__(256) void gather64_add_kernel(
    const _Float16* __restrict__ Y2, const float* __restrict__ F,
    const int* __restrict__ offs, const int* __restrict__ deg,
    const unsigned short* __restrict__ elist, float* __restrict__ out) {
  int node = blockIdx.x * 8 + (threadIdx.x >> 5);
  if (node >= N) return;
  int l = threadIdx.x & 31;
  const int e0 = offs[node];              // e0 % 8 == 0
  const int d = deg[node];
  const int e1 = e0 + d;
  float a0 = 0.f, a1 = 0.f;
  int e = e0;
  for (; e + 16 <= e1; e += 16) {
    u16x8 q0 = *(const u16x8*)(elist + e);
    u16x8 q1 = *(const u16x8*)(elist + e + 8);
    int s[16] = {q0[0], q0[1], q0[2], q0[3], q0[4], q0[5], q0[6], q0[7],
                 q1[0], q1[1], q1[2], q1[3], q1[4], q1[5], q1[6], q1[7]};
    f16x2 v[16];
#pragma unroll
    for (int u = 0; u < 16; ++u)
      v[u] = *(const f16x2*)(Y2 + (size_t)s[u] * 64 + l * 2);
#pragma unroll
    for (int u = 0; u < 16; ++u) { a0 += (float)v[u][0]; a1 += (float)v[u][1]; }
  }
  for (; e + 4 <= e1; e += 4) {
    u16x4 q = *(const u16x4*)(elist + e);
    int s[4] = {q[0], q[1], q[2], q[3]};
    f16x2 v[4];
#pragma unroll
    for (int u = 0; u < 4; ++u)
      v[u] = *(const f16x2*)(Y2 + (size_t)s[u] * 64 + l * 2);
#pragma unroll
    for (int u = 0; u < 4; ++u) { a0 += (float)v[u][0]; a1 += (float)v[u][1]; }
  }
  for (; e < e1; ++e) {
    f16x2 v = *(const f16x2*)(Y2 + (size_t)elist[e] * 64 + l * 2);
    a0 += (float)v[0]; a1 += (float)v[1];
  }
  float inv = 1.0f / (float)max(d, 1);
  float2 f = ((const float2*)(F + (size_t)node * 64))[l];
  float2 o;
  o.x = f.x + a0 * inv;
  o.y = f.y + a1 * inv;
  ((float2*)(out + (size_t)node * 64))[l] = o;
}

extern "C" void kernel_launch(void* const* d_in, const int* in_sizes, int n_in,
                              void* d_out, int out_size, void* d_ws, size_t ws_size,
                              hipStream_t stream) {
  const float* x   = (const float*)d_in[0];
  const float* u1  = (const float*)d_in[1];
  const float* u2  = (const float*)d_in[2];
  const float* wl0 = (const float*)d_in[3];
  const float* bl0 = (const float*)d_in[4];
  const float* wr0 = (const float*)d_in[5];
  const float* wl1 = (const float*)d_in[6];
  const float* bl1 = (const float*)d_in[7];
  const float* wr1 = (const float*)d_in[8];
  const float* wl2 = (const float*)d_in[9];
  const float* bl2 = (const float*)d_in[10];
  const float* wr2 = (const float*)d_in[11];
  const int* edge  = (const int*)d_in[12];
  const int* src = edge;
  const int* dst = edge + E;

  // workspace layout
  _Float16* HA  = (_Float16*)d_ws;                 // N x 128 f16
  _Float16* HB  = HA + (size_t)N * 128;            // N x 128 f16
  _Float16* Y2  = HB + (size_t)N * 128;            // N x 64 f16
  float* F      = (float*)(Y2 + (size_t)N * 64);   // N x 64 f32
  int* offs     = (int*)(F + (size_t)N * 64);      // N
  int* deg      = offs + N;                        // N
  unsigned short* elist = (unsigned short*)(deg + N);  // NBUCK*SLOT u16
  unsigned* T   = (unsigned*)(elist + NBUCK * SLOT);   // NBUCK*SLOT u32
  int* bcur     = (int*)(T + NBUCK * SLOT);        // NBUCK (counts)
  uintptr_t p = (uintptr_t)(bcur + NBUCK);
  p = (p + 15) & ~(uintptr_t)15;
  _Float16* wf0 = (_Float16*)p;                    // 8*8*512
  _Float16* wf1 = wf0 + 8 * 8 * 512;
  _Float16* wfZ = wf1 + 8 * 8 * 512;               // 8*4*512
  unsigned* mk1 = (unsigned*)(wfZ + 8 * 4 * 512);  // N*4 u32 (bit mask)
  unsigned* mk2 = mk1 + (size_t)N * 4;             // N*4 u32

  // 0) bcur counts = 0
  hipMemsetAsync(bcur, 0, NBUCK * sizeof(int), stream);
  // 1) merged setup + scatter + masks
  setup_scatter_kernel<<<NEB + CONVB + 320 + 2 * MASKB, 256, 0, stream>>>(
      src, dst, bcur, T, x, u1, u2, wl0, wr0, wl1, wr1, wl2, wr2,
      HA, wf0, wf1, wfZ, mk1, mk2);
  // 2) place
  bucket_place_kernel<<<NBUCK, 256, 0, stream>>>(T, bcur, offs, deg, elist);

  const int GM16 = N / 16;             // 3125 fused-layer blocks
  const int GG64 = (N + 7) / 8;        // half-wave per node

  // ---- Layer 0 (fused gather+GEMM) ----
  fused_layer_kernel<<<GM16, 256, 0, stream>>>(HA, offs, deg, elist, wf0, bl0,
                                               mk1, HB);
  // ---- Layer 1 + Layer-2 GEMM (fused; h1 never hits global) ----
  fused_layerZ_kernel<<<GM16, 256, 0, stream>>>(HB, offs, deg, elist, wf1, bl1,
                                                mk2, wfZ, bl2, Y2, F);
  // ---- Layer 2 gather + add ----
  gather64_add_kernel<<<GG64, 256, 0, stream>>>(Y2, F, offs, deg, elist,
                                                (float*)d_out);
}